// Round 3
// baseline (2056.134 us; speedup 1.0000x reference)
//
#include <hip/hip_runtime.h>
#include <hip/hip_bf16.h>
#include <math.h>

#define NB 2048      // batch
#define KN 20        // neighbors
#define DD 128       // edge feat dim
#define TT 100       // time dim
#define CC 128       // channels
#define TKN 40       // tokens (2K)
#define HTD 20       // token FFN hidden
#define HCD 512      // channel FFN hidden

#define FS 520       // feat LDS stride (bf16): 520*2B=1040B=260 banks == 4 mod 32 -> 2-way free
#define HS 264       // h LDS stride (bf16): 528B = 132 banks == 4 mod 32 -> 2-way free
#define TS 132       // tok LDS stride (fp32): 132 == 4 mod 32 -> 2-way free
#define AS2 136      // LN'd A LDS stride (bf16): verified free in R2

typedef __attribute__((ext_vector_type(8))) short bf16x8;
typedef __attribute__((ext_vector_type(4))) float f32x4;

__device__ __forceinline__ float gelu_f(float x) {
    return 0.5f * x * (1.0f + erff(x * 0.70710678118654752f));
}

__device__ __forceinline__ unsigned short f2bf(float x) {
    __hip_bfloat16 h = __float2bfloat16(x);   // RNE
    return *reinterpret_cast<unsigned short*>(&h);
}

// ---------------------------------------------------------------------------
// Kernel 0: weight prep — bf16 + transpose to [n][k] rows for MFMA B-frags.
// grid 7: blocks 0-3 = channel FFN mixers; 4 = projT; 5,6 = eprojT[j].
// K-pad regions zeroed (feat K-pad also zeroed in fused kernel -> no NaN).
// ---------------------------------------------------------------------------
__global__ __launch_bounds__(256) void prep_weights(
    const float* __restrict__ cW1, const float* __restrict__ cW2,
    const float* __restrict__ proj_W, const float* __restrict__ eproj_W,
    unsigned short* __restrict__ w1t, unsigned short* __restrict__ w2t,
    unsigned short* __restrict__ projT, unsigned short* __restrict__ eprojT)
{
    const int blk = blockIdx.x;
    const int tid = threadIdx.x;
    if (blk < 4) {
        const int m = blk;
        // W1T[m][n][k] = cW1[m][k][n], n<512 k<128
        for (int idx = tid; idx < HCD * CC; idx += 256) {
            const int n = idx >> 7, k = idx & 127;
            w1t[(size_t)m * HCD * CC + idx] = f2bf(cW1[(size_t)m * CC * HCD + (size_t)k * HCD + n]);
        }
        // W2T[m][n][k] = cW2[m][k][n], n<128 k<512
        for (int idx = tid; idx < HCD * CC; idx += 256) {
            const int n = idx >> 9, k = idx & 511;
            w2t[(size_t)m * HCD * CC + idx] = f2bf(cW2[(size_t)m * HCD * CC + (size_t)k * CC + n]);
        }
    } else if (blk == 4) {
        // projT[n][k] (k padded to 256) = proj_W[k][n], k<228
        for (int idx = tid; idx < CC * 256; idx += 256) {
            const int n = idx >> 8, k = idx & 255;
            projT[idx] = (k < DD + TT) ? f2bf(proj_W[(size_t)k * CC + n]) : (unsigned short)0;
        }
    } else {
        const int j = blk - 5;
        // eprojT[j][n][k] (k padded to 512) = eproj_W[j][k][n], k<484
        for (int idx = tid; idx < CC * 512; idx += 256) {
            const int n = idx >> 9, k = idx & 511;
            eprojT[(size_t)j * CC * 512 + idx] =
                (k < 3 * DD + TT) ? f2bf(eproj_W[(size_t)j * (3 * DD + TT) * CC + (size_t)k * CC + n])
                                  : (unsigned short)0;
        }
    }
}

// ---------------------------------------------------------------------------
// Fused mega-kernel: one block per (sample, branch). 256 threads = 4 waves.
// Token matrix [40][128] lives in LDS end-to-end:
//   gather+tenc -> proj MFMA -> (token_mix -> channel_mix MFMA) x2 -> mean
//   -> atomicAdd(out, softmax(pcc) weight * mean).
// M-tail handling: MFMA row m of C depends only on row m of A, so garbage
// LDS rows (20-31 in feat, 40-47 in Al/h) pollute only discarded C rows.
// Feat/weight K-pad regions are explicitly zeroed (no NaN leak via K).
// ---------------------------------------------------------------------------
__global__ __launch_bounds__(256, 2) void fused_mixer(
    const float* __restrict__ edge_table,
    const int* __restrict__ src_eids, const int* __restrict__ dst_eids,
    const int* __restrict__ src2_e1, const int* __restrict__ src2_e2,
    const int* __restrict__ dst2_e1, const int* __restrict__ dst2_e2,
    const float* __restrict__ dt_src, const float* __restrict__ dt_dst,
    const float* __restrict__ dt2_src, const float* __restrict__ dt2_dst,
    const float* __restrict__ pcc1, const float* __restrict__ pcc2,
    const float* __restrict__ time_w, const float* __restrict__ time_b,
    const unsigned short* __restrict__ projT, const float* __restrict__ proj_b,
    const unsigned short* __restrict__ eprojT, const float* __restrict__ eproj_b,
    const float* __restrict__ tln_g, const float* __restrict__ tln_b,
    const float* __restrict__ tW1, const float* __restrict__ tb1,
    const float* __restrict__ tW2, const float* __restrict__ tb2,
    const float* __restrict__ cln_g, const float* __restrict__ cln_b,
    const unsigned short* __restrict__ w1t, const unsigned short* __restrict__ w2t,
    const float* __restrict__ cb1, const float* __restrict__ cb2,
    float* __restrict__ out)
{
    __shared__ __align__(16) short fh[32 * FS];     // 33280 B: feat (32 rows) / h (48 rows x HS)
    __shared__ __align__(16) float tokl[TKN * TS];  // 21120 B
    __shared__ __align__(16) short Al[48 * AS2];    // 13056 B

    const int b = blockIdx.x;
    const int branch = blockIdx.y;
    const int tid = threadIdx.x;
    const int wv = tid >> 6;
    const int lane = tid & 63;
    const int l15 = lane & 15;
    const int q = lane >> 4;

    // =================== Stage 1: build features + proj MFMA ===============
    for (int pass = 0; pass < 2; ++pass) {
        // ---- gather: wave wv owns tokens wv*5 .. wv*5+4 of this pass ----
        const int* eidsA = pass ? dst_eids : src_eids;
        for (int i = 0; i < 5; ++i) {
            const int t = wv * 5 + i;           // local row 0..19
            short* f = fh + t * FS;
            if (branch == 0) {
                const int eid = eidsA[b * KN + t];
                const float dt = (pass ? dt_dst : dt_src)[b * KN + t];
                const float2 ev = *(const float2*)(edge_table + (size_t)eid * DD + 2 * lane);
                *(unsigned int*)(f + 2 * lane) =
                    (unsigned int)f2bf(ev.x) | ((unsigned int)f2bf(ev.y) << 16);
                const float msk = (eid == 0) ? 0.0f : 1.0f;
                f[DD + lane] = (short)f2bf(msk * cosf(dt * time_w[lane] + time_b[lane]));
                if (lane < TT - 64)
                    f[DD + 64 + lane] = (short)f2bf(msk * cosf(dt * time_w[64 + lane] + time_b[64 + lane]));
                if (lane < 28) f[228 + lane] = 0;   // K-pad 228..255
            } else {
                const int e1 = (pass ? dst2_e1 : src2_e1)[b * KN + t];
                const int e2 = (pass ? dst2_e2 : src2_e2)[b * KN + t];
                const int e0 = eidsA[b * KN + t];
                const float dt = (pass ? dt2_dst : dt2_src)[b * KN + t];
                const float2 v1 = *(const float2*)(edge_table + (size_t)e1 * DD + 2 * lane);
                const float2 v2 = *(const float2*)(edge_table + (size_t)e2 * DD + 2 * lane);
                const float2 v0 = *(const float2*)(edge_table + (size_t)e0 * DD + 2 * lane);
                *(unsigned int*)(f + 2 * lane) =
                    (unsigned int)f2bf(v1.x) | ((unsigned int)f2bf(v1.y) << 16);
                *(unsigned int*)(f + DD + 2 * lane) =
                    (unsigned int)f2bf(v2.x) | ((unsigned int)f2bf(v2.y) << 16);
                *(unsigned int*)(f + 2 * DD + 2 * lane) =
                    (unsigned int)f2bf(v0.x) | ((unsigned int)f2bf(v0.y) << 16);
                const float msk = (e1 == 0) ? 0.0f : 1.0f;
                f[3 * DD + lane] = (short)f2bf(msk * cosf(dt * time_w[lane] + time_b[lane]));
                if (lane < TT - 64)
                    f[3 * DD + 64 + lane] = (short)f2bf(msk * cosf(dt * time_w[64 + lane] + time_b[64 + lane]));
                if (lane < 28) f[484 + lane] = 0;   // K-pad 484..511
            }
        }
        __syncthreads();

        // ---- proj MFMA: [32(20)][K] x [K][128]; wave owns 32 cols ----
        const unsigned short* Bw;
        const float* bias;
        int Kstr, KS;
        if (branch == 0) { Bw = projT; bias = proj_b; Kstr = 256; KS = 8; }
        else { Bw = eprojT + (size_t)pass * CC * 512; bias = eproj_b + pass * CC; Kstr = 512; KS = 16; }

        f32x4 pacc[2][2];
        #pragma unroll
        for (int mt = 0; mt < 2; ++mt)
            #pragma unroll
            for (int nt = 0; nt < 2; ++nt) pacc[mt][nt] = (f32x4){0.f, 0.f, 0.f, 0.f};

        for (int ks = 0; ks < KS; ++ks) {
            const bf16x8 a0 = *(const bf16x8*)(fh + l15 * FS + ks * 32 + q * 8);
            const bf16x8 a1 = *(const bf16x8*)(fh + (16 + l15) * FS + ks * 32 + q * 8);
            #pragma unroll
            for (int nt = 0; nt < 2; ++nt) {
                const int n = wv * 32 + nt * 16 + l15;
                const bf16x8 bf = *(const bf16x8*)(Bw + (size_t)n * Kstr + ks * 32 + q * 8);
                pacc[0][nt] = __builtin_amdgcn_mfma_f32_16x16x32_bf16(a0, bf, pacc[0][nt], 0, 0, 0);
                pacc[1][nt] = __builtin_amdgcn_mfma_f32_16x16x32_bf16(a1, bf, pacc[1][nt], 0, 0, 0);
            }
        }
        #pragma unroll
        for (int mt = 0; mt < 2; ++mt)
            #pragma unroll
            for (int nt = 0; nt < 2; ++nt) {
                const int col = wv * 32 + nt * 16 + l15;
                #pragma unroll
                for (int reg = 0; reg < 4; ++reg) {
                    const int row = mt * 16 + q * 4 + reg;
                    if (row < 20)
                        tokl[(pass * 20 + row) * TS + col] = pacc[mt][nt][reg] + bias[col];
                }
            }
        __syncthreads();   // feat free for next pass / later h reuse
    }

    // =================== Stage 2: mixer layers =============================
    for (int layer = 0; layer < 2; ++layer) {
        const int m = branch * 2 + layer;

        // ---- token mix: thread c = channel (tid < 128) ----
        if (tid < 128) {
            const int c = tid;
            const float* g  = tln_g + m * TKN;
            const float* bb = tln_b + m * TKN;
            const float* W1 = tW1 + (size_t)m * TKN * HTD;
            const float* b1 = tb1 + m * HTD;
            const float* W2 = tW2 + (size_t)m * HTD * TKN;
            const float* b2 = tb2 + m * TKN;

            float v[TKN];
            float s = 0.0f;
            #pragma unroll
            for (int k = 0; k < TKN; ++k) { v[k] = tokl[k * TS + c]; s += v[k]; }
            const float mean = s * (1.0f / TKN);
            float vs = 0.0f;
            #pragma unroll
            for (int k = 0; k < TKN; ++k) { const float d = v[k] - mean; vs += d * d; }
            const float rinv = rsqrtf(vs * (1.0f / TKN) + 1e-5f);

            float h1[HTD];
            #pragma unroll
            for (int j = 0; j < HTD; ++j) h1[j] = b1[j];
            for (int k = 0; k < TKN; ++k) {
                const float nk = (v[k] - mean) * rinv * g[k] + bb[k];
                #pragma unroll
                for (int j = 0; j < HTD; ++j) h1[j] += nk * W1[k * HTD + j];
            }
            #pragma unroll
            for (int j = 0; j < HTD; ++j) h1[j] = gelu_f(h1[j]);
            for (int k = 0; k < TKN; ++k) {
                float s2 = b2[k];
                #pragma unroll
                for (int j = 0; j < HTD; ++j) s2 += h1[j] * W2[j * TKN + k];
                tokl[k * TS + c] = v[k] + s2;
            }
        }
        __syncthreads();

        // ---- channel mix LN -> Al (wave-per-row) ----
        {
            const float g0 = cln_g[m * CC + lane], g1 = cln_g[m * CC + lane + 64];
            const float bb0 = cln_b[m * CC + lane], bb1 = cln_b[m * CC + lane + 64];
            for (int r = wv; r < TKN; r += 4) {
                const float x0 = tokl[r * TS + lane];
                const float x1 = tokl[r * TS + lane + 64];
                float s = x0 + x1, qq = x0 * x0 + x1 * x1;
                #pragma unroll
                for (int o = 32; o > 0; o >>= 1) {
                    s += __shfl_xor(s, o);
                    qq += __shfl_xor(qq, o);
                }
                const float mean = s * (1.0f / CC);
                const float rinv = rsqrtf(qq * (1.0f / CC) - mean * mean + 1e-5f);
                Al[r * AS2 + lane]      = (short)f2bf((x0 - mean) * rinv * g0 + bb0);
                Al[r * AS2 + lane + 64] = (short)f2bf((x1 - mean) * rinv * g1 + bb1);
            }
        }
        __syncthreads();

        const unsigned short* W1 = w1t + (size_t)m * HCD * CC;
        const unsigned short* W2 = w2t + (size_t)m * HCD * CC;
        const float* B1 = cb1 + m * HCD;
        const float* B2 = cb2 + m * CC;

        f32x4 a2[3][2];
        #pragma unroll
        for (int mt = 0; mt < 3; ++mt)
            #pragma unroll
            for (int nt = 0; nt < 2; ++nt) a2[mt][nt] = (f32x4){0.f, 0.f, 0.f, 0.f};

        for (int hc = 0; hc < 2; ++hc) {
            // ---- GEMM1: [48(40)][128] x [128][256-chunk]; wave owns 64 cols ----
            f32x4 a1[3][4];
            #pragma unroll
            for (int mt = 0; mt < 3; ++mt)
                #pragma unroll
                for (int nt = 0; nt < 4; ++nt) a1[mt][nt] = (f32x4){0.f, 0.f, 0.f, 0.f};

            #pragma unroll
            for (int ks = 0; ks < 4; ++ks) {
                bf16x8 am[3];
                #pragma unroll
                for (int mt = 0; mt < 3; ++mt)
                    am[mt] = *(const bf16x8*)(Al + (mt * 16 + l15) * AS2 + ks * 32 + q * 8);
                #pragma unroll
                for (int nt = 0; nt < 4; ++nt) {
                    const int n = hc * 256 + wv * 64 + nt * 16 + l15;
                    const bf16x8 bf = *(const bf16x8*)(W1 + (size_t)n * CC + ks * 32 + q * 8);
                    #pragma unroll
                    for (int mt = 0; mt < 3; ++mt)
                        a1[mt][nt] = __builtin_amdgcn_mfma_f32_16x16x32_bf16(am[mt], bf, a1[mt][nt], 0, 0, 0);
                }
            }
            __syncthreads();   // h region free (prev chunk's GEMM2 readers done)

            // ---- bias + gelu -> h (bf16, C-layout scatter) ----
            #pragma unroll
            for (int nt = 0; nt < 4; ++nt) {
                const int n = hc * 256 + wv * 64 + nt * 16 + l15;
                const float b1v = B1[n];
                #pragma unroll
                for (int mt = 0; mt < 3; ++mt)
                    #pragma unroll
                    for (int reg = 0; reg < 4; ++reg) {
                        const int row = mt * 16 + q * 4 + reg;
                        if (row < TKN)
                            fh[row * HS + wv * 64 + nt * 16 + l15] =
                                (short)f2bf(gelu_f(a1[mt][nt][reg] + b1v));
                    }
            }
            __syncthreads();

            // ---- GEMM2: [48(40)][256-chunk] x [chunk][128]; wave owns 32 cols ----
            #pragma unroll
            for (int ks = 0; ks < 8; ++ks) {
                bf16x8 hm[3];
                #pragma unroll
                for (int mt = 0; mt < 3; ++mt)
                    hm[mt] = *(const bf16x8*)(fh + (mt * 16 + l15) * HS + ks * 32 + q * 8);
                #pragma unroll
                for (int nt = 0; nt < 2; ++nt) {
                    const int n = wv * 32 + nt * 16 + l15;
                    const bf16x8 bf = *(const bf16x8*)(W2 + (size_t)n * HCD + hc * 256 + ks * 32 + q * 8);
                    #pragma unroll
                    for (int mt = 0; mt < 3; ++mt)
                        a2[mt][nt] = __builtin_amdgcn_mfma_f32_16x16x32_bf16(hm[mt], bf, a2[mt][nt], 0, 0, 0);
                }
            }
            __syncthreads();   // before next chunk overwrites h
        }

        // ---- residual + bias into tokl (wave-exclusive 32-col band) ----
        #pragma unroll
        for (int nt = 0; nt < 2; ++nt) {
            const int col = wv * 32 + nt * 16 + l15;
            const float b2v = B2[col];
            #pragma unroll
            for (int mt = 0; mt < 3; ++mt)
                #pragma unroll
                for (int reg = 0; reg < 4; ++reg) {
                    const int row = mt * 16 + q * 4 + reg;
                    if (row < TKN)
                        tokl[row * TS + col] += a2[mt][nt][reg] + b2v;
                }
        }
        __syncthreads();
    }

    // =================== Stage 3: mean + pcc softmax -> atomic out =========
    if (tid < CC) {
        float s = 0.0f;
        #pragma unroll 4
        for (int k = 0; k < TKN; ++k) s += tokl[k * TS + tid];
        const float p1 = pcc1[b], p2 = pcc2[b];
        const float mx = fmaxf(p1, p2);
        const float e0 = expf(p1 - mx), e1 = expf(p2 - mx);
        const float w = ((branch == 0) ? e0 : e1) / (e0 + e1);
        atomicAdd(out + (size_t)b * CC + tid, w * s * (1.0f / TKN));
    }
}

// ---------------------------------------------------------------------------
extern "C" void kernel_launch(void* const* d_in, const int* in_sizes, int n_in,
                              void* d_out, int out_size, void* d_ws, size_t ws_size,
                              hipStream_t stream)
{
    const float* edge_table = (const float*)d_in[0];
    const int*   src_eids   = (const int*)d_in[1];
    const int*   dst_eids   = (const int*)d_in[2];
    const int*   src2_e1    = (const int*)d_in[3];
    const int*   src2_e2    = (const int*)d_in[4];
    const int*   dst2_e1    = (const int*)d_in[5];
    const int*   dst2_e2    = (const int*)d_in[6];
    const float* dt_src     = (const float*)d_in[7];
    const float* dt_dst     = (const float*)d_in[8];
    const float* dt2_src    = (const float*)d_in[9];
    const float* dt2_dst    = (const float*)d_in[10];
    const float* pcc1       = (const float*)d_in[11];
    const float* pcc2       = (const float*)d_in[12];
    const float* time_w     = (const float*)d_in[13];
    const float* time_b     = (const float*)d_in[14];
    const float* proj_W     = (const float*)d_in[15];
    const float* proj_b     = (const float*)d_in[16];
    const float* eproj_W    = (const float*)d_in[17];
    const float* eproj_b    = (const float*)d_in[18];
    const float* mix_tln_g  = (const float*)d_in[19];
    const float* mix_tln_b  = (const float*)d_in[20];
    const float* mix_tW1    = (const float*)d_in[21];
    const float* mix_tb1    = (const float*)d_in[22];
    const float* mix_tW2    = (const float*)d_in[23];
    const float* mix_tb2    = (const float*)d_in[24];
    const float* mix_cln_g  = (const float*)d_in[25];
    const float* mix_cln_b  = (const float*)d_in[26];
    const float* mix_cW1    = (const float*)d_in[27];
    const float* mix_cb1    = (const float*)d_in[28];
    const float* mix_cW2    = (const float*)d_in[29];
    const float* mix_cb2    = (const float*)d_in[30];

    // workspace layout (bf16 prepped weights)
    unsigned short* w1t    = (unsigned short*)d_ws;                  // 4*512*128 = 262144 el
    unsigned short* w2t    = w1t + 4 * HCD * CC;                     // 262144 el
    unsigned short* projT  = w2t + 4 * HCD * CC;                     // 128*256 = 32768 el
    unsigned short* eprojT = projT + CC * 256;                       // 2*128*512 = 131072 el

    hipMemsetAsync(d_out, 0, (size_t)out_size * sizeof(float), stream);

    prep_weights<<<7, 256, 0, stream>>>(mix_cW1, mix_cW2, proj_W, eproj_W,
                                        w1t, w2t, projT, eprojT);

    fused_mixer<<<dim3(NB, 2), 256, 0, stream>>>(
        edge_table, src_eids, dst_eids, src2_e1, src2_e2, dst2_e1, dst2_e2,
        dt_src, dt_dst, dt2_src, dt2_dst, pcc1, pcc2, time_w, time_b,
        projT, proj_b, eprojT, eproj_b,
        mix_tln_g, mix_tln_b, mix_tW1, mix_tb1, mix_tW2, mix_tb2,
        mix_cln_g, mix_cln_b, w1t, w2t, mix_cb1, mix_cb2,
        (float*)d_out);
}

// Round 4
// 1132.158 us; speedup vs baseline: 1.8161x; 1.8161x over previous
//
#include <hip/hip_runtime.h>
#include <hip/hip_bf16.h>
#include <math.h>

#define NB 2048      // batch
#define KN 20        // neighbors
#define CC 128       // channels
#define TKN 40       // tokens (2K)
#define HTD 20       // token FFN hidden
#define HCD 512      // channel FFN hidden

#define FS2 520      // feat LDS stride (bf16): 1040B, 260 banks == 4 mod 32 -> frag reads 2-way free
#define TS2 136      // tokl/hbuf stride (bf16): 272B, 68 banks == 4 mod 32 -> frag reads 2-way free

typedef __attribute__((ext_vector_type(8))) short bf16x8;
typedef __attribute__((ext_vector_type(4))) float f32x4;

__device__ __forceinline__ float gelu_f(float x) {
    return 0.5f * x * (1.0f + erff(x * 0.70710678118654752f));
}
__device__ __forceinline__ unsigned short f2bf(float x) {
    __hip_bfloat16 h = __float2bfloat16(x);   // RNE
    return *reinterpret_cast<unsigned short*>(&h);
}
__device__ __forceinline__ float bf2f(unsigned int u16v) {
    return __uint_as_float((u16v & 0xffffu) << 16);
}
__device__ __forceinline__ unsigned int pk2(float a, float b) {
    return (unsigned int)f2bf(a) | ((unsigned int)f2bf(b) << 16);
}

// ---------------------------------------------------------------------------
// prep: bf16 [n][k] weights; LN-fold for channel FFN GEMM1:
//   w1t[m][n][k] = g_k * W1[k][n];  S1[m][n] = sum_k g_k W1[k][n];
//   C1[m][n] = sum_k beta_k W1[k][n] + b1[n]
// grid 52 x 256.
// ---------------------------------------------------------------------------
__global__ __launch_bounds__(256) void prep_weights(
    const float* __restrict__ cW1, const float* __restrict__ cW2,
    const float* __restrict__ proj_W, const float* __restrict__ eproj_W,
    const float* __restrict__ cln_g, const float* __restrict__ cln_b,
    const float* __restrict__ cb1,
    unsigned short* __restrict__ w1t, unsigned short* __restrict__ w2t,
    unsigned short* __restrict__ projT, unsigned short* __restrict__ eprojT,
    float* __restrict__ S1, float* __restrict__ C1)
{
    const int blk = blockIdx.x, tid = threadIdx.x;
    if (blk < 16) {                 // w1t (g-folded, transposed)
        const int m = blk >> 2, base = (blk & 3) * 16384;
        for (int i = 0; i < 64; ++i) {
            const int idx = base + i * 256 + tid;       // n*128+k
            const int n = idx >> 7, k = idx & 127;
            w1t[(size_t)m * 65536 + idx] =
                f2bf(cln_g[m * CC + k] * cW1[(size_t)m * 65536 + (size_t)k * HCD + n]);
        }
    } else if (blk < 32) {          // w2t (transposed)
        const int m = (blk - 16) >> 2, base = ((blk - 16) & 3) * 16384;
        for (int i = 0; i < 64; ++i) {
            const int idx = base + i * 256 + tid;       // n*512+k
            const int n = idx >> 9, k = idx & 511;
            w2t[(size_t)m * 65536 + idx] = f2bf(cW2[(size_t)m * 65536 + (size_t)k * CC + n]);
        }
    } else if (blk < 40) {          // S1 / C1 (fp32)
        const int t = blk - 32, m = t >> 1, n = (t & 1) * 256 + tid;
        float s1 = 0.f, c1 = 0.f;
        for (int k = 0; k < CC; ++k) {
            const float w = cW1[(size_t)m * 65536 + (size_t)k * HCD + n];
            s1 += cln_g[m * CC + k] * w;
            c1 += cln_b[m * CC + k] * w;
        }
        S1[m * HCD + n] = s1;
        C1[m * HCD + n] = c1 + cb1[m * HCD + n];
    } else if (blk < 44) {          // projT [n][256], K-pad zeroed
        const int base = (blk - 40) * 8192;
        for (int i = 0; i < 32; ++i) {
            const int idx = base + i * 256 + tid;       // n*256+k
            const int n = idx >> 8, k = idx & 255;
            projT[idx] = (k < 228) ? f2bf(proj_W[(size_t)k * CC + n]) : (unsigned short)0;
        }
    } else {                        // eprojT [j][n][512], blk 44..51
        const int t = blk - 44, j = t >> 2, base = (t & 3) * 16384;
        for (int i = 0; i < 64; ++i) {
            const int idx = base + i * 256 + tid;       // n*512+k
            const int n = idx >> 9, k = idx & 511;
            eprojT[(size_t)j * 65536 + idx] =
                (k < 484) ? f2bf(eproj_W[(size_t)j * 484 * CC + (size_t)k * CC + n])
                          : (unsigned short)0;
        }
    }
}

// ---------------------------------------------------------------------------
// Kernel A: gather + time-enc + MFMA projection -> bf16 tok[unit][40][128].
// grid (2048, 2) x 256. Two passes of 20 tokens (pass == eproj half, tile-safe).
// LDS 33 KB -> 4 blocks/CU.
// ---------------------------------------------------------------------------
__global__ __launch_bounds__(256, 4) void build_tokens2(
    const float* __restrict__ edge_table,
    const int* __restrict__ src_eids, const int* __restrict__ dst_eids,
    const int* __restrict__ src2_e1, const int* __restrict__ src2_e2,
    const int* __restrict__ dst2_e1, const int* __restrict__ dst2_e2,
    const float* __restrict__ dt_src, const float* __restrict__ dt_dst,
    const float* __restrict__ dt2_src, const float* __restrict__ dt2_dst,
    const float* __restrict__ time_w, const float* __restrict__ time_b,
    const unsigned short* __restrict__ projT, const float* __restrict__ proj_b,
    const unsigned short* __restrict__ eprojT, const float* __restrict__ eproj_b,
    unsigned short* __restrict__ tok)
{
    __shared__ __align__(16) short feat[32 * FS2];   // 33280 B

    const int sample = blockIdx.x;
    const int branch = blockIdx.y;
    const int tid = threadIdx.x;
    const int wv = tid >> 6, lane = tid & 63;
    const int l15 = lane & 15, q = lane >> 4;

    unsigned short* tokp = tok + (size_t)(branch * NB + sample) * (TKN * CC);

    // zero M-pad rows 20..31 once (NaN-safe garbage rows)
    for (int i = tid; i < 12 * FS2 / 2; i += 256)
        ((unsigned int*)(feat + 20 * FS2))[i] = 0u;
    __syncthreads();

    for (int pass = 0; pass < 2; ++pass) {
        // ---- gather: wave owns tokens wv*5 .. wv*5+4 ----
        for (int i = 0; i < 5; ++i) {
            const int tl = wv * 5 + i;
            short* f = feat + tl * FS2;
            if (branch == 0) {
                const int eid = (pass ? dst_eids : src_eids)[sample * KN + tl];
                const float dt = (pass ? dt_dst : dt_src)[sample * KN + tl];
                const float2 ev = *(const float2*)(edge_table + (size_t)eid * CC + 2 * lane);
                *(unsigned int*)(f + 2 * lane) = pk2(ev.x, ev.y);
                const float msk = (eid == 0) ? 0.f : 1.f;
                f[128 + lane] = (short)f2bf(msk * cosf(dt * time_w[lane] + time_b[lane]));
                if (lane < 36)
                    f[192 + lane] = (short)f2bf(msk * cosf(dt * time_w[64 + lane] + time_b[64 + lane]));
                if (lane < 28) f[228 + lane] = 0;   // K-pad 228..255
            } else {
                const int e1 = (pass ? dst2_e1 : src2_e1)[sample * KN + tl];
                const int e2 = (pass ? dst2_e2 : src2_e2)[sample * KN + tl];
                const int e0 = (pass ? dst_eids : src_eids)[sample * KN + tl];
                const float dt = (pass ? dt2_dst : dt2_src)[sample * KN + tl];
                const float2 v1 = *(const float2*)(edge_table + (size_t)e1 * CC + 2 * lane);
                const float2 v2 = *(const float2*)(edge_table + (size_t)e2 * CC + 2 * lane);
                const float2 v0 = *(const float2*)(edge_table + (size_t)e0 * CC + 2 * lane);
                *(unsigned int*)(f + 2 * lane)       = pk2(v1.x, v1.y);
                *(unsigned int*)(f + 128 + 2 * lane) = pk2(v2.x, v2.y);
                *(unsigned int*)(f + 256 + 2 * lane) = pk2(v0.x, v0.y);
                const float msk = (e1 == 0) ? 0.f : 1.f;
                f[384 + lane] = (short)f2bf(msk * cosf(dt * time_w[lane] + time_b[lane]));
                if (lane < 36)
                    f[448 + lane] = (short)f2bf(msk * cosf(dt * time_w[64 + lane] + time_b[64 + lane]));
                if (lane < 28) f[484 + lane] = 0;   // K-pad 484..511
            }
        }
        __syncthreads();

        // ---- proj MFMA: M=32 (rows>=20 discarded), wave owns 32 N-cols ----
        const unsigned short* Bw = (branch == 0) ? projT : (eprojT + (size_t)pass * 65536);
        const float* bias = (branch == 0) ? proj_b : (eproj_b + pass * CC);
        const int Kstr = (branch == 0) ? 256 : 512;
        const int KS = (branch == 0) ? 8 : 16;

        f32x4 acc[2][2];
        #pragma unroll
        for (int mt = 0; mt < 2; ++mt)
            #pragma unroll
            for (int nt = 0; nt < 2; ++nt) acc[mt][nt] = (f32x4){0.f, 0.f, 0.f, 0.f};

        for (int ks = 0; ks < KS; ++ks) {
            const bf16x8 a0 = *(const bf16x8*)(feat + l15 * FS2 + ks * 32 + q * 8);
            const bf16x8 a1 = *(const bf16x8*)(feat + (16 + l15) * FS2 + ks * 32 + q * 8);
            #pragma unroll
            for (int nt = 0; nt < 2; ++nt) {
                const int n = wv * 32 + nt * 16 + l15;
                const bf16x8 bf = *(const bf16x8*)(Bw + (size_t)n * Kstr + ks * 32 + q * 8);
                acc[0][nt] = __builtin_amdgcn_mfma_f32_16x16x32_bf16(a0, bf, acc[0][nt], 0, 0, 0);
                acc[1][nt] = __builtin_amdgcn_mfma_f32_16x16x32_bf16(a1, bf, acc[1][nt], 0, 0, 0);
            }
        }
        #pragma unroll
        for (int mt = 0; mt < 2; ++mt)
            #pragma unroll
            for (int nt = 0; nt < 2; ++nt) {
                const int col = wv * 32 + nt * 16 + l15;
                const float bv = bias[col];
                #pragma unroll
                for (int reg = 0; reg < 4; ++reg) {
                    const int row = mt * 16 + q * 4 + reg;
                    if (row < 20)
                        tokp[(size_t)(pass * 20 + row) * CC + col] = f2bf(acc[mt][nt][reg] + bv);
                }
            }
        __syncthreads();
    }
}

// ---------------------------------------------------------------------------
// Kernel B: full mixer stack. Block = 2 units (same branch), 256 thr, 4 waves.
// M=80 rows = exactly 5 m-tiles. tokl (bf16 residual stream) + hbuf in LDS.
// Channel LN folded into GEMM1 via (S1, C1) -> A-frags read tokl directly.
// LDS 44 KB -> 3 blocks/CU.
// ---------------------------------------------------------------------------
__global__ __launch_bounds__(256, 3) void mixer_stack(
    const unsigned short* __restrict__ tok,
    const float* __restrict__ pcc1, const float* __restrict__ pcc2,
    const float* __restrict__ tln_g, const float* __restrict__ tln_b,
    const float* __restrict__ tW1, const float* __restrict__ tb1,
    const float* __restrict__ tW2, const float* __restrict__ tb2,
    const unsigned short* __restrict__ w1t, const unsigned short* __restrict__ w2t,
    const float* __restrict__ S1, const float* __restrict__ C1,
    const float* __restrict__ cb2,
    float* __restrict__ out)
{
    __shared__ __align__(16) short tokl[80 * TS2];   // 21760 B
    __shared__ __align__(16) short hbuf[80 * TS2];   // 21760 B
    __shared__ float mu[80], rv[80];

    const int u0 = blockIdx.x * 2;
    const int branch = u0 >> 11;
    const int tid = threadIdx.x;
    const int wv = tid >> 6, lane = tid & 63;
    const int l15 = lane & 15, q = lane >> 4;

    // ---- load 2 units' tokens (coalesced) ----
    const unsigned short* tg = tok + (size_t)u0 * (TKN * CC);
    #pragma unroll
    for (int i = 0; i < 10; ++i) {
        const int flat = i * 1024 + tid * 4;
        const uint2 v = *(const uint2*)(tg + flat);
        *(uint2*)(tokl + (flat >> 7) * TS2 + (flat & 127)) = v;
    }
    __syncthreads();

    for (int layer = 0; layer < 2; ++layer) {
        const int m = branch * 2 + layer;

        // ---- token mix: thread = (unit, channel), all 256 threads ----
        {
            const int lu = tid >> 7, c = tid & 127;
            short* xr = tokl + lu * TKN * TS2 + c;
            const float* g  = tln_g + m * TKN;
            const float* bb = tln_b + m * TKN;
            const float* W1 = tW1 + (size_t)m * TKN * HTD;
            const float* b1 = tb1 + m * HTD;
            const float* W2 = tW2 + (size_t)m * HTD * TKN;
            const float* b2 = tb2 + m * TKN;

            float s = 0.f, ss = 0.f;
            #pragma unroll
            for (int k = 0; k < TKN; ++k) {
                const float v = bf2f((unsigned short)xr[k * TS2]);
                s += v; ss += v * v;
            }
            const float mean = s * (1.f / TKN);
            const float rinv = rsqrtf(ss * (1.f / TKN) - mean * mean + 1e-5f);

            float h1[HTD];
            #pragma unroll
            for (int j = 0; j < HTD; ++j) h1[j] = b1[j];
            for (int k = 0; k < TKN; ++k) {
                const float nk = (bf2f((unsigned short)xr[k * TS2]) - mean) * rinv * g[k] + bb[k];
                #pragma unroll
                for (int j = 0; j < HTD; ++j) h1[j] += nk * W1[k * HTD + j];
            }
            #pragma unroll
            for (int j = 0; j < HTD; ++j) h1[j] = gelu_f(h1[j]);
            for (int k = 0; k < TKN; ++k) {
                float s2 = b2[k];
                #pragma unroll
                for (int j = 0; j < HTD; ++j) s2 += h1[j] * W2[j * TKN + k];
                xr[k * TS2] = (short)f2bf(bf2f((unsigned short)xr[k * TS2]) + s2);
            }
        }
        __syncthreads();

        // ---- per-row stats (for LN-folded GEMM1 fixup) ----
        for (int r = wv * 20; r < wv * 20 + 20; ++r) {
            const unsigned int pr = *(const unsigned int*)(tokl + r * TS2 + 2 * lane);
            const float a = bf2f(pr), b = bf2f(pr >> 16);
            float s = a + b, ss = a * a + b * b;
            #pragma unroll
            for (int o = 32; o > 0; o >>= 1) {
                s += __shfl_xor(s, o);
                ss += __shfl_xor(ss, o);
            }
            if (lane == 0) {
                const float mn = s * (1.f / CC);
                mu[r] = mn;
                rv[r] = rsqrtf(ss * (1.f / CC) - mn * mn + 1e-5f);
            }
        }
        __syncthreads();

        // ---- channel FFN: 4 chunks of 128 hidden cols ----
        const unsigned short* W1 = w1t + (size_t)m * 65536;
        const unsigned short* W2 = w2t + (size_t)m * 65536;
        const float* S1m = S1 + m * HCD;
        const float* C1m = C1 + m * HCD;

        f32x4 acc2[5][2];
        #pragma unroll
        for (int mt = 0; mt < 5; ++mt)
            #pragma unroll
            for (int nt = 0; nt < 2; ++nt) acc2[mt][nt] = (f32x4){0.f, 0.f, 0.f, 0.f};

        for (int hc = 0; hc < 4; ++hc) {
            // GEMM1: x @ W1g, A straight from tokl
            f32x4 acc1[5][2];
            #pragma unroll
            for (int mt = 0; mt < 5; ++mt)
                #pragma unroll
                for (int nt = 0; nt < 2; ++nt) acc1[mt][nt] = (f32x4){0.f, 0.f, 0.f, 0.f};

            #pragma unroll
            for (int ks = 0; ks < 4; ++ks) {
                bf16x8 am[5];
                #pragma unroll
                for (int mt = 0; mt < 5; ++mt)
                    am[mt] = *(const bf16x8*)(tokl + (mt * 16 + l15) * TS2 + ks * 32 + q * 8);
                #pragma unroll
                for (int nt = 0; nt < 2; ++nt) {
                    const int n = hc * 128 + wv * 32 + nt * 16 + l15;
                    const bf16x8 bf = *(const bf16x8*)(W1 + (size_t)n * CC + ks * 32 + q * 8);
                    #pragma unroll
                    for (int mt = 0; mt < 5; ++mt)
                        acc1[mt][nt] = __builtin_amdgcn_mfma_f32_16x16x32_bf16(am[mt], bf, acc1[mt][nt], 0, 0, 0);
                }
            }
            __syncthreads();   // prev chunk's GEMM2 readers done with hbuf

            // LN fixup + gelu -> bf16 hbuf (C-layout scatter)
            #pragma unroll
            for (int nt = 0; nt < 2; ++nt) {
                const int n = hc * 128 + wv * 32 + nt * 16 + l15;
                const float s1n = S1m[n], c1n = C1m[n];
                #pragma unroll
                for (int mt = 0; mt < 5; ++mt)
                    #pragma unroll
                    for (int reg = 0; reg < 4; ++reg) {
                        const int row = mt * 16 + q * 4 + reg;
                        const float val = rv[row] * (acc1[mt][nt][reg] - mu[row] * s1n) + c1n;
                        hbuf[row * TS2 + wv * 32 + nt * 16 + l15] = (short)f2bf(gelu_f(val));
                    }
            }
            __syncthreads();

            // GEMM2: h @ W2 chunk, accumulate
            #pragma unroll
            for (int ks = 0; ks < 4; ++ks) {
                bf16x8 hm[5];
                #pragma unroll
                for (int mt = 0; mt < 5; ++mt)
                    hm[mt] = *(const bf16x8*)(hbuf + (mt * 16 + l15) * TS2 + ks * 32 + q * 8);
                #pragma unroll
                for (int nt = 0; nt < 2; ++nt) {
                    const int n = wv * 32 + nt * 16 + l15;
                    const bf16x8 bf = *(const bf16x8*)(W2 + (size_t)n * HCD + hc * 128 + ks * 32 + q * 8);
                    #pragma unroll
                    for (int mt = 0; mt < 5; ++mt)
                        acc2[mt][nt] = __builtin_amdgcn_mfma_f32_16x16x32_bf16(hm[mt], bf, acc2[mt][nt], 0, 0, 0);
                }
            }
        }

        // ---- residual + bias into tokl (wave-exclusive 32-col band) ----
        #pragma unroll
        for (int nt = 0; nt < 2; ++nt) {
            const int col = wv * 32 + nt * 16 + l15;
            const float b2v = cb2[m * CC + col];
            #pragma unroll
            for (int mt = 0; mt < 5; ++mt)
                #pragma unroll
                for (int reg = 0; reg < 4; ++reg) {
                    const int row = mt * 16 + q * 4 + reg;
                    short* p = tokl + row * TS2 + col;
                    *p = (short)f2bf(bf2f((unsigned short)*p) + acc2[mt][nt][reg] + b2v);
                }
        }
        __syncthreads();
    }

    // ---- mean + pcc softmax -> atomic out ----
    {
        const int lu = tid >> 7, c = tid & 127;
        const int sample = (u0 + lu) & (NB - 1);
        float s = 0.f;
        #pragma unroll 4
        for (int k = 0; k < TKN; ++k) s += bf2f((unsigned short)tokl[(lu * TKN + k) * TS2 + c]);
        const float p1 = pcc1[sample], p2 = pcc2[sample];
        const float mx = fmaxf(p1, p2);
        const float e0 = expf(p1 - mx), e1 = expf(p2 - mx);
        const float w = ((branch == 0) ? e0 : e1) / (e0 + e1);
        atomicAdd(out + (size_t)sample * CC + c, w * s * (1.f / TKN));
    }
}

// ---------------------------------------------------------------------------
extern "C" void kernel_launch(void* const* d_in, const int* in_sizes, int n_in,
                              void* d_out, int out_size, void* d_ws, size_t ws_size,
                              hipStream_t stream)
{
    const float* edge_table = (const float*)d_in[0];
    const int*   src_eids   = (const int*)d_in[1];
    const int*   dst_eids   = (const int*)d_in[2];
    const int*   src2_e1    = (const int*)d_in[3];
    const int*   src2_e2    = (const int*)d_in[4];
    const int*   dst2_e1    = (const int*)d_in[5];
    const int*   dst2_e2    = (const int*)d_in[6];
    const float* dt_src     = (const float*)d_in[7];
    const float* dt_dst     = (const float*)d_in[8];
    const float* dt2_src    = (const float*)d_in[9];
    const float* dt2_dst    = (const float*)d_in[10];
    const float* pcc1       = (const float*)d_in[11];
    const float* pcc2       = (const float*)d_in[12];
    const float* time_w     = (const float*)d_in[13];
    const float* time_b     = (const float*)d_in[14];
    const float* proj_W     = (const float*)d_in[15];
    const float* proj_b     = (const float*)d_in[16];
    const float* eproj_W    = (const float*)d_in[17];
    const float* eproj_b    = (const float*)d_in[18];
    const float* mix_tln_g  = (const float*)d_in[19];
    const float* mix_tln_b  = (const float*)d_in[20];
    const float* mix_tW1    = (const float*)d_in[21];
    const float* mix_tb1    = (const float*)d_in[22];
    const float* mix_tW2    = (const float*)d_in[23];
    const float* mix_tb2    = (const float*)d_in[24];
    const float* mix_cln_g  = (const float*)d_in[25];
    const float* mix_cln_b  = (const float*)d_in[26];
    const float* mix_cW1    = (const float*)d_in[27];
    const float* mix_cb1    = (const float*)d_in[28];
    const float* mix_cW2    = (const float*)d_in[29];
    const float* mix_cb2    = (const float*)d_in[30];

    // workspace layout
    char* ws = (char*)d_ws;
    unsigned short* tok    = (unsigned short*)ws;                    // 4096*5120*2 = 41,943,040
    unsigned short* w1t    = (unsigned short*)(ws + 41943040);       // 524,288
    unsigned short* w2t    = (unsigned short*)(ws + 42467328);       // 524,288
    unsigned short* projT  = (unsigned short*)(ws + 42991616);       // 65,536
    unsigned short* eprojT = (unsigned short*)(ws + 43057152);       // 262,144
    float*          S1     = (float*)(ws + 43319296);                // 8,192
    float*          C1     = (float*)(ws + 43327488);                // 8,192

    hipMemsetAsync(d_out, 0, (size_t)out_size * sizeof(float), stream);

    prep_weights<<<52, 256, 0, stream>>>(
        mix_cW1, mix_cW2, proj_W, eproj_W, mix_cln_g, mix_cln_b, mix_cb1,
        w1t, w2t, projT, eprojT, S1, C1);

    build_tokens2<<<dim3(NB, 2), 256, 0, stream>>>(
        edge_table, src_eids, dst_eids, src2_e1, src2_e2, dst2_e1, dst2_e2,
        dt_src, dt_dst, dt2_src, dt2_dst, time_w, time_b,
        projT, proj_b, eprojT, eproj_b, tok);

    mixer_stack<<<NB, 256, 0, stream>>>(
        tok, pcc1, pcc2,
        mix_tln_g, mix_tln_b, mix_tW1, mix_tb1, mix_tW2, mix_tb2,
        w1t, w2t, S1, C1, mix_cb2,
        (float*)d_out);
}